// Round 8
// baseline (1268.760 us; speedup 1.0000x reference)
//
#include <hip/hip_runtime.h>
#include <hip/hip_fp16.h>
#include <math.h>

// Problem constants (from reference): N=100000, E=1600000, F_IN=8, H=128,
// L=4, E_FEAT=16, G=256, OUT=256. N/E derived from in_sizes at launch.
#define GG 256

typedef __attribute__((ext_vector_type(8))) short short8;
typedef __attribute__((ext_vector_type(4))) float f32x4;

__device__ __forceinline__ unsigned short f2bf(float x) {
  union { float f; unsigned u; } v; v.f = x;
  unsigned r = v.u + 0x7fff + ((v.u >> 16) & 1);   // round-to-nearest-even
  return (unsigned short)(r >> 16);
}

__device__ __forceinline__ unsigned pack_h2(float a, float b) {
  __half2 h = __floats2half2_rn(a, b);
  return *(unsigned*)&h;
}

// ---------- h = x @ emb_W + emb_b  ([N,8]@[8,128]); also writes bf16 shadow ----------
__global__ __launch_bounds__(256) void k_emb(const float* __restrict__ x,
    const float* __restrict__ W, const float* __restrict__ b,
    float* __restrict__ h, unsigned short* __restrict__ hb, int N) {
  int idx = blockIdx.x * 256 + threadIdx.x;      // one float4 of output per thread
  if (idx >= N * 32) return;
  int n = idx >> 5, q = idx & 31;
  const float* xr = x + (size_t)n * 8;
  float xs[8];
#pragma unroll
  for (int k = 0; k < 8; ++k) xs[k] = xr[k];
  float4 acc = ((const float4*)b)[q];
#pragma unroll
  for (int k = 0; k < 8; ++k) {
    float4 w = ((const float4*)(W + (size_t)k * 128))[q];
    acc.x += xs[k] * w.x; acc.y += xs[k] * w.y;
    acc.z += xs[k] * w.z; acc.w += xs[k] * w.w;
  }
  ((float4*)h)[idx] = acc;
  ushort4 hv4 = make_ushort4(f2bf(acc.x), f2bf(acc.y), f2bf(acc.z), f2bf(acc.w));
  *(ushort4*)(hb + (size_t)idx * 4) = hv4;
}

// ---------- convert edge weights to packed fp16: eW16[l][k][c] = (w[2c],w[2c+1]) ----------
__global__ __launch_bounds__(256) void k_wconv(const float* __restrict__ eW,
    unsigned* __restrict__ eW16) {           // 4*16*64 = 4096 pairs
  int i = blockIdx.x * 256 + threadIdx.x;
  if (i >= 4096) return;
  float2 wp = *(const float2*)(eW + (size_t)i * 2);
  eW16[i] = pack_h2(wp.x, wp.y);
}

// ---------- transpose nn_W to bf16: WT[l][n][k] = bf16(nn_W[l][k][n]) ----------
__global__ __launch_bounds__(256) void k_nnconv(const float* __restrict__ W,
    unsigned short* __restrict__ WT) {
  int i = blockIdx.x * 256 + threadIdx.x;    // i = ((l*128)+k)*128 + n
  if (i >= 4 * 128 * 128) return;
  int n = i & 127, k = (i >> 7) & 127, l = i >> 14;
  WT[((size_t)(l * 128 + n)) * 128 + k] = f2bf(W[i]);
}

// ---------- CSR build ----------
__global__ void k_hist(const int* __restrict__ dst, int* __restrict__ deg, int E) {
  int e = blockIdx.x * blockDim.x + threadIdx.x;
  if (e < E) atomicAdd(&deg[dst[e]], 1);
}

__global__ __launch_bounds__(256) void k_scan_reduce(const int* __restrict__ deg,
    int* __restrict__ bsum, int N) {
  __shared__ int sd[256];
  int i = blockIdx.x * 256 + threadIdx.x;
  sd[threadIdx.x] = (i < N) ? deg[i] : 0;
  __syncthreads();
  for (int s = 128; s > 0; s >>= 1) {
    if (threadIdx.x < s) sd[threadIdx.x] += sd[threadIdx.x + s];
    __syncthreads();
  }
  if (threadIdx.x == 0) bsum[blockIdx.x] = sd[0];
}

// single-block exclusive scan over nb (<=512) block sums
__global__ __launch_bounds__(512) void k_scan_mid(int* bsum, int nb) {
  __shared__ int sd[512];
  int t = threadIdx.x;
  int v = (t < nb) ? bsum[t] : 0;
  sd[t] = v; __syncthreads();
  for (int d = 1; d < 512; d <<= 1) {
    int xv = (t >= d) ? sd[t - d] : 0;
    __syncthreads();
    sd[t] += xv;
    __syncthreads();
  }
  if (t < nb) bsum[t] = sd[t] - v;   // exclusive
}

__global__ __launch_bounds__(256) void k_scan_final(const int* __restrict__ deg,
    const int* __restrict__ bsum, int* __restrict__ offs,
    int* __restrict__ cursor, int N) {
  __shared__ int sd[256];
  int t = threadIdx.x;
  int i = blockIdx.x * 256 + t;
  int v = (i < N) ? deg[i] : 0;
  sd[t] = v; __syncthreads();
  for (int d = 1; d < 256; d <<= 1) {           // Hillis-Steele inclusive scan
    int xv = (t >= d) ? sd[t - d] : 0;
    __syncthreads();
    sd[t] += xv;
    __syncthreads();
  }
  int off = bsum[blockIdx.x] + sd[t] - v;       // exclusive
  if (i < N) {
    offs[i] = off; cursor[i] = off;
    if (i == N - 1) offs[N] = off + v;
  }
}

// fill CSR: permute src + attr (converted to fp16, 32 B/edge) into dst order
__global__ void k_fill(const int* __restrict__ src, const int* __restrict__ dst,
    const float* __restrict__ attr, int* __restrict__ cursor,
    int* __restrict__ csrc, uint4* __restrict__ cattr16, int E) {
  int e = blockIdx.x * blockDim.x + threadIdx.x;
  if (e >= E) return;
  int d = dst[e];
  int pos = atomicAdd(&cursor[d], 1);
  csrc[pos] = src[e];
  const float4* a = (const float4*)(attr + (size_t)e * 16);
  float4 a0 = a[0], a1 = a[1], a2 = a[2], a3 = a[3];
  uint4 o0, o1;
  o0.x = pack_h2(a0.x, a0.y); o0.y = pack_h2(a0.z, a0.w);
  o0.z = pack_h2(a1.x, a1.y); o0.w = pack_h2(a1.z, a1.w);
  o1.x = pack_h2(a2.x, a2.y); o1.y = pack_h2(a2.z, a2.w);
  o1.z = pack_h2(a3.x, a3.y); o1.w = pack_h2(a3.z, a3.w);
  cattr16[(size_t)pos * 2] = o0;
  cattr16[(size_t)pos * 2 + 1] = o1;
}

// ---------- graph boundaries (batch is sorted) ----------
__global__ void k_gstart(const int* __restrict__ batch, int* __restrict__ gstart,
                         int N, int Gn) {
  int i = blockIdx.x * blockDim.x + threadIdx.x;
  if (i >= N) return;
  int b = batch[i];
  if (i == 0) { for (int g = 0; g <= b; ++g) gstart[g] = 0; }
  else { int bp = batch[i - 1]; for (int g = bp + 1; g <= b; ++g) gstart[g] = i; }
  if (i == N - 1) { for (int g = b + 1; g <= Gn; ++g) gstart[g] = N; }
}

// ---------- fused edge embed + gather + relu + aggregate ----------
// hpa16[n] = bf16( h[n] + sum_j relu( attr[j]@edge_W + edge_b + h[src[j]] ) )
// ONE WAVE per node, 2 columns per lane, packed-fp16 MLP.
// csrc is software-pipelined ONE GROUP AHEAD so the 8 gathers at loop top
// have their addresses already resident (breaks the s_load->gather chain).
__global__ __launch_bounds__(256) void k_edge_agg(const float* __restrict__ h,
    const unsigned* __restrict__ hb32,       // bf16 shadow viewed as uint
    const uint4* __restrict__ cattr16, const int* __restrict__ csrc,
    const int* __restrict__ offs, const unsigned* __restrict__ eW16,
    const float* __restrict__ eb, unsigned* __restrict__ hpa16,
    float* __restrict__ cstats, int N) {
  int t = threadIdx.x;
  if (blockIdx.x == 0) cstats[t] = 0.f;    // 256 floats: colsum|colsumsq
  int n = blockIdx.x * 4 + (t >> 6);
  if (n >= N) return;
  int l = t & 63;                           // lane -> columns 2l, 2l+1
  __half2 w2[16];
#pragma unroll
  for (int k = 0; k < 16; ++k) {
    unsigned u = eW16[k * 64 + l];
    w2[k] = *(__half2*)&u;
  }
  float2 bias = *(const float2*)(eb + 2 * l);
  const unsigned* hb_l = hb32 + l;          // + s*64 per edge (row = 64 uints)
  int jb = offs[n], je = offs[n + 1];
  jb = __builtin_amdgcn_readfirstlane(jb);
  je = __builtin_amdgcn_readfirstlane(je);

// MLP body given attr words P0/P1, gathered bf16 pair U, accumulator ACC
#define MLPADD(P0, P1, U, ACC)                                              \
  {                                                                         \
    __half2 ev = __floats2half2_rn(0.f, 0.f);                               \
    const unsigned pw[8] = {P0.x, P0.y, P0.z, P0.w, P1.x, P1.y, P1.z, P1.w};\
    _Pragma("unroll")                                                       \
    for (int k = 0; k < 8; ++k) {                                           \
      __half2 ap = *(__half2*)&pw[k];                                       \
      ev = __hfma2(__half2half2(__low2half(ap)), w2[2 * k], ev);            \
      ev = __hfma2(__half2half2(__high2half(ap)), w2[2 * k + 1], ev);       \
    }                                                                       \
    float e0 = __low2float(ev), e1 = __high2float(ev);                      \
    union { unsigned uu; float ff; } c0, c1;                                \
    c0.uu = (U) << 16; c1.uu = (U) & 0xffff0000u;                           \
    ACC.x += fmaxf(e0 + bias.x + c0.ff, 0.f);                               \
    ACC.y += fmaxf(e1 + bias.y + c1.ff, 0.f);                               \
  }

  float2 acc[8];
#pragma unroll
  for (int i = 0; i < 8; ++i) acc[i] = make_float2(0.f, 0.f);

  int j = jb;
  if (j + 8 <= je) {
    int s_cur[8];
#pragma unroll
    for (int i = 0; i < 8; ++i) s_cur[i] = csrc[j + i];
    for (; j + 8 <= je; j += 8) {
      // gathers first: addresses already resident
      unsigned u[8];
#pragma unroll
      for (int i = 0; i < 8; ++i) u[i] = hb_l[(size_t)s_cur[i] * 64];
      // prefetch next group's src ids (clamped, branch-free, uniform)
      int s_nxt[8];
#pragma unroll
      for (int i = 0; i < 8; ++i) {
        int jn = j + 8 + i;
        if (jn > je - 1) jn = je - 1;
        s_nxt[i] = csrc[jn];
      }
#pragma unroll
      for (int i = 0; i < 8; ++i) {
        uint4 p0 = cattr16[(size_t)(j + i) * 2];
        uint4 p1 = cattr16[(size_t)(j + i) * 2 + 1];
        MLPADD(p0, p1, u[i], acc[i])
      }
#pragma unroll
      for (int i = 0; i < 8; ++i) s_cur[i] = s_nxt[i];
    }
  }
  for (; j < je; ++j) {
    int s = csrc[j];
    uint4 p0 = cattr16[(size_t)j * 2];
    uint4 p1 = cattr16[(size_t)j * 2 + 1];
    unsigned u = hb_l[(size_t)s * 64];
    MLPADD(p0, p1, u, acc[0])
  }
#undef MLPADD
  float2 hvv = *(const float2*)(h + (size_t)n * 128 + 2 * l);
  float rx = hvv.x + (((acc[0].x + acc[1].x) + (acc[2].x + acc[3].x)) +
                      ((acc[4].x + acc[5].x) + (acc[6].x + acc[7].x)));
  float ry = hvv.y + (((acc[0].y + acc[1].y) + (acc[2].y + acc[3].y)) +
                      ((acc[4].y + acc[5].y) + (acc[6].y + acc[7].y)));
  hpa16[(size_t)n * 64 + l] = ((unsigned)f2bf(ry) << 16) | (unsigned)f2bf(rx);
}

// ---------- MFMA node GEMM: hc = bf16(hpa) @ nn_W + nn_b, + fused BN stats ----------
// 128 rows/block, 4 waves x (2 row-tiles x 8 col-tiles) of 16x16x32 bf16 MFMA.
// Only W staged in LDS (34.8 KB -> 4 blocks/CU); A fragments are read directly
// from global in MFMA A-layout (each A row touched exactly once per block).
__global__ __launch_bounds__(256) void k_gemm_mfma(
    const unsigned short* __restrict__ A16, const unsigned short* __restrict__ WT16,
    const float* __restrict__ bias, float* __restrict__ hc,
    float* __restrict__ cstats, int N) {
  __shared__ short w_lds[128 * 136];
  int t = threadIdx.x;
  int rowbase = blockIdx.x * 128;
  {
    int r = t >> 1;
    int off = (t & 1) * 64;              // shorts
    const short* gw = (const short*)WT16 + (size_t)r * 128 + off;
    short* lw = &w_lds[r * 136 + off];
#pragma unroll
    for (int jj = 0; jj < 8; ++jj)
      *(uint4*)(lw + jj * 8) = *(const uint4*)(gw + jj * 8);
  }
  int w = t >> 6;
  int lane = t & 63;
  int l15 = lane & 15, quad = lane >> 4;
  // A fragments straight from global (A-layout: row = tile_row + l15, k = quad*8)
  short8 af[2][4];
#pragma unroll
  for (int rt = 0; rt < 2; ++rt) {
    int row = rowbase + w * 32 + rt * 16 + l15;
    bool ok = row < N;
#pragma unroll
    for (int kc = 0; kc < 4; ++kc) {
      short8 v = (short8){0, 0, 0, 0, 0, 0, 0, 0};
      if (ok) v = *(const short8*)((const short*)A16 + (size_t)row * 128 + kc * 32 + quad * 8);
      af[rt][kc] = v;
    }
  }
  __syncthreads();
  f32x4 acc[2][8];
#pragma unroll
  for (int rt = 0; rt < 2; ++rt)
#pragma unroll
    for (int nt = 0; nt < 8; ++nt)
      acc[rt][nt] = (f32x4){0.f, 0.f, 0.f, 0.f};
#pragma unroll
  for (int kc = 0; kc < 4; ++kc) {
    int k0 = kc * 32 + quad * 8;
#pragma unroll
    for (int nt = 0; nt < 8; ++nt) {
      short8 bf = *(const short8*)&w_lds[(nt * 16 + l15) * 136 + k0];
      acc[0][nt] = __builtin_amdgcn_mfma_f32_16x16x32_bf16(af[0][kc], bf, acc[0][nt], 0, 0, 0);
      acc[1][nt] = __builtin_amdgcn_mfma_f32_16x16x32_bf16(af[1][kc], bf, acc[1][nt], 0, 0, 0);
    }
  }
  float sA[8], sQ[8];
#pragma unroll
  for (int nt = 0; nt < 8; ++nt) { sA[nt] = 0.f; sQ[nt] = 0.f; }
#pragma unroll
  for (int nt = 0; nt < 8; ++nt) {
    int col = nt * 16 + l15;
    float bv = bias[col];
#pragma unroll
    for (int rt = 0; rt < 2; ++rt) {
      int rbase = rowbase + w * 32 + rt * 16 + quad * 4;
#pragma unroll
      for (int reg = 0; reg < 4; ++reg) {
        int row = rbase + reg;
        float v = acc[rt][nt][reg] + bv;
        if (row < N) {
          hc[(size_t)row * 128 + col] = v;
          sA[nt] += v; sQ[nt] += v * v;
        }
      }
    }
  }
#pragma unroll
  for (int nt = 0; nt < 8; ++nt) {
    sA[nt] += __shfl_xor(sA[nt], 16);
    sA[nt] += __shfl_xor(sA[nt], 32);
    sQ[nt] += __shfl_xor(sQ[nt], 16);
    sQ[nt] += __shfl_xor(sQ[nt], 32);
  }
  __syncthreads();                    // done with w_lds contents
  float* sdA = (float*)w_lds;         // [4][128]
  float* sdQ = (float*)w_lds + 512;
  if (quad == 0) {
#pragma unroll
    for (int nt = 0; nt < 8; ++nt) {
      sdA[w * 128 + nt * 16 + l15] = sA[nt];
      sdQ[w * 128 + nt * 16 + l15] = sQ[nt];
    }
  }
  __syncthreads();
  if (t < 128) {
    float s = sdA[t] + sdA[128 + t] + sdA[256 + t] + sdA[384 + t];
    float s2 = sdQ[t] + sdQ[128 + t] + sdQ[256 + t] + sdQ[384 + t];
    atomicAdd(&cstats[t], s);
    atomicAdd(&cstats[128 + t], s2);
  }
}

// ---------- BN apply + exact GELU + residual: h += gelu(bn(hc)); bf16 shadow ----------
__global__ __launch_bounds__(256) void k_bn(const float* __restrict__ hc,
    const float* __restrict__ cstats,
    const float* __restrict__ g, const float* __restrict__ bb,
    float* __restrict__ h, unsigned short* __restrict__ hb, int N) {
  int idx = blockIdx.x * 256 + threadIdx.x;
  if (idx >= N * 32) return;
  int q = idx & 31;
  float invN = 1.f / (float)N;
  float4 cs = ((const float4*)cstats)[q];
  float4 cq = ((const float4*)cstats)[q + 32];
  float4 gv = ((const float4*)g)[q];
  float4 bv = ((const float4*)bb)[q];
  float4 v = ((const float4*)hc)[idx];
  float4 hv = ((const float4*)h)[idx];
#define BN1(X)                                                      \
  { float mu = cs.X * invN;                                         \
    float var = cq.X * invN - mu * mu;                              \
    float xn = (v.X - mu) * rsqrtf(var + 1e-5f) * gv.X + bv.X;      \
    hv.X += 0.5f * xn * (1.f + erff(xn * 0.70710678118654752f)); }
  BN1(x) BN1(y) BN1(z) BN1(w)
#undef BN1
  ((float4*)h)[idx] = hv;
  if (hb) {
    ushort4 hv4 = make_ushort4(f2bf(hv.x), f2bf(hv.y), f2bf(hv.z), f2bf(hv.w));
    *(ushort4*)(hb + (size_t)idx * 4) = hv4;
  }
}

// ---------- rep[g] = (sum over nodes of graph g of h[n]) @ lin_W + cnt*lin_b ----------
__global__ __launch_bounds__(256) void k_poolfinal(const float* __restrict__ h,
    const int* __restrict__ gstart, const float* __restrict__ W,
    const float* __restrict__ b, float* __restrict__ out) {
  int g = blockIdx.x;
  int t = threadIdx.x, c = t & 127, half = t >> 7;
  int n0 = gstart[g], n1 = gstart[g + 1];
  float s = 0.f;
  for (int n = n0 + half; n < n1; n += 2) s += h[(size_t)n * 128 + c];
  __shared__ float ls[256];
  __shared__ float pr[128];
  ls[t] = s; __syncthreads();
  if (t < 128) pr[t] = ls[t] + ls[t + 128];
  __syncthreads();
  float cnt = (float)(n1 - n0);
  float acc = cnt * b[t];
#pragma unroll 8
  for (int k = 0; k < 128; ++k) acc += pr[k] * W[(size_t)k * 256 + t];
  out[(size_t)g * 256 + t] = acc;
}

extern "C" void kernel_launch(void* const* d_in, const int* in_sizes, int n_in,
                              void* d_out, int out_size, void* d_ws, size_t ws_size,
                              hipStream_t stream) {
  const float* x     = (const float*)d_in[0];
  const int*   eidx  = (const int*)d_in[1];
  const float* eattr = (const float*)d_in[2];
  const int*   batch = (const int*)d_in[3];
  const float* embW  = (const float*)d_in[4];
  const float* embB  = (const float*)d_in[5];
  const float* edgeW = (const float*)d_in[6];
  const float* edgeB = (const float*)d_in[7];
  const float* nnW   = (const float*)d_in[8];
  const float* nnB   = (const float*)d_in[9];
  const float* bnG   = (const float*)d_in[10];
  const float* bnB   = (const float*)d_in[11];
  const float* linW  = (const float*)d_in[12];
  const float* linB  = (const float*)d_in[13];
  float* out = (float*)d_out;

  int N = in_sizes[0] / 8;
  int E = in_sizes[1] / 2;
  const int* src = eidx;
  const int* dst = eidx + E;

  // workspace carve-up (~220 MB)
  char* wptr = (char*)d_ws;
  auto alloc = [&](size_t bytes) {
    char* p = wptr; wptr += (bytes + 255) & ~(size_t)255; return p;
  };
  float* h      = (float*)alloc((size_t)N * 128 * 4);
  float* hc     = (float*)alloc((size_t)N * 128 * 4);   // fp32 GEMM output
  unsigned short* hb = (unsigned short*)alloc((size_t)N * 128 * 2);  // bf16 h shadow
  unsigned* hpa16 = (unsigned*)alloc((size_t)N * 64 * 4);  // bf16 h+agg (GEMM input)
  uint4* cattr16 = (uint4*)alloc((size_t)E * 32);       // fp16 attrs, 32 B/edge
  int*   csrc   = (int*)alloc((size_t)E * 4);
  int*   offs   = (int*)alloc((size_t)(N + 1) * 4);
  int*   cursor = (int*)alloc((size_t)N * 4);
  int*   deg    = (int*)alloc((size_t)N * 4);
  int nb = (N + 255) / 256;
  int*   bsum   = (int*)alloc((size_t)nb * 4);
  float* cstats = (float*)alloc(256 * 4);               // colsum | colsumsq
  unsigned* eW16 = (unsigned*)alloc(4096 * 4);          // [4][16][64] packed half2
  unsigned short* WT16 = (unsigned short*)alloc(4 * 128 * 128 * 2);  // bf16 W^T
  int*   gstart = (int*)alloc((size_t)(GG + 1) * 4);

  int q32 = (N * 32 + 255) / 256;

  hipMemsetAsync(deg, 0, (size_t)N * 4, stream);
  k_emb<<<q32, 256, 0, stream>>>(x, embW, embB, h, hb, N);
  k_wconv<<<16, 256, 0, stream>>>(edgeW, eW16);
  k_nnconv<<<256, 256, 0, stream>>>(nnW, WT16);
  k_hist<<<(E + 255) / 256, 256, 0, stream>>>(dst, deg, E);
  k_scan_reduce<<<nb, 256, 0, stream>>>(deg, bsum, N);
  k_scan_mid<<<1, 512, 0, stream>>>(bsum, nb);
  k_scan_final<<<nb, 256, 0, stream>>>(deg, bsum, offs, cursor, N);
  k_fill<<<(E + 255) / 256, 256, 0, stream>>>(src, dst, eattr, cursor, csrc, cattr16, E);
  k_gstart<<<(N + 255) / 256, 256, 0, stream>>>(batch, gstart, N, GG);

  int gblk = (N + 127) / 128;
  for (int l = 0; l < 4; ++l) {
    k_edge_agg<<<(N + 3) / 4, 256, 0, stream>>>(h, (const unsigned*)hb, cattr16, csrc,
        offs, eW16 + (size_t)l * 1024, edgeB + (size_t)l * 128, hpa16, cstats, N);
    k_gemm_mfma<<<gblk, 256, 0, stream>>>((const unsigned short*)hpa16,
        WT16 + (size_t)l * 128 * 128, nnB + (size_t)l * 128, hc, cstats, N);
    k_bn<<<q32, 256, 0, stream>>>(hc, cstats,
        bnG + (size_t)l * 128, bnB + (size_t)l * 128, h, (l == 3) ? nullptr : hb, N);
  }
  k_poolfinal<<<GG, 256, 0, stream>>>(h, gstart, linW, linB, out);
}